// Round 3
// baseline (339.166 us; speedup 1.0000x reference)
//
#include <hip/hip_runtime.h>

// MPLayer: out[i,m] = (1/K) sum_{j,l,n} edges[i,j,n] * nodes[nlist[i,j],l] * w[l,m,n]
// N=50000, K=32, F=128, E=16. Two-phase MFMA (fp16 in, fp32 acc):
//   phase 1: T[i][c'] (permuted c-order), per 16-wide l-tile one 16x16x32 MFMA
//   phase 2: out = T @ W2t^T / K, with W2t columns stored in the SAME permuted order
// v3: depth-4 rolling register prefetch of the neighbor gather -> per-r critical
//     path no longer contains a full gather latency (v2 was 1 exposed latency per
//     (chunk,r) = 32 per wave; v3 is ~1 per chunk).

typedef _Float16 half8  __attribute__((ext_vector_type(8)));
typedef _Float16 half4v __attribute__((ext_vector_type(4)));
typedef float    float4v __attribute__((ext_vector_type(4)));
typedef int      int4v  __attribute__((ext_vector_type(4)));
typedef unsigned int uint;

#define NF 128
#define NK 32
#define NE 16
#define RPB 32

__global__ __launch_bounds__(256) void k_prep_nodes(const float* __restrict__ src,
                                                    _Float16* __restrict__ dst, int n4) {
    int i = blockIdx.x * 256 + threadIdx.x;
    if (i < n4) {
        float4v v = ((const float4v*)src)[i];
        half4v h;
        h[0] = (_Float16)v[0]; h[1] = (_Float16)v[1];
        h[2] = (_Float16)v[2]; h[3] = (_Float16)v[3];
        ((half4v*)dst)[i] = h;
    }
}

// W2t permuted: storage index o = m*2048 + ch*512 + ltq*64 + n*4 + g
// corresponds to w[l, m, n] with l = ch*32 + (ltq>>2)*16 + (ltq&3)*4 + g.
__global__ __launch_bounds__(256) void k_prep_w(const float* __restrict__ w,
                                                _Float16* __restrict__ w2t) {
    int o  = blockIdx.x * 256 + threadIdx.x;   // 262144 total, exact grid
    int m  = o >> 11;
    int cf = o & 2047;
    int ch = cf >> 9;
    int cp = cf & 511;
    int ltq = cp >> 6;
    int n   = (cp >> 2) & 15;
    int g   = cp & 3;
    int l = ch * 32 + (ltq >> 2) * 16 + (ltq & 3) * 4 + g;
    w2t[o] = (_Float16)w[(l * NF + m) * NE + n];
}

// MFMA 16x16x32 f16 layouts (verified by v1/v2 passing):
//   A: lane holds A[m = lane&15][k = (lane>>4)*8 + jj]
//   B: lane holds B[k = (lane>>4)*8 + jj][n = lane&15]
//   C/D: lane holds D[row = (lane>>4)*4 + g][col = lane&15]
__global__ __launch_bounds__(256, 4) void k_mp(const _Float16* __restrict__ nodes_h,
                                               const int* __restrict__ nlist,
                                               const float* __restrict__ edges,
                                               const _Float16* __restrict__ w2t,
                                               float* __restrict__ out, int N) {
    // s_T: 32 i-rows x 512 permuted-c halves per chunk, XOR-swizzled (32KB).
    // s_G: per-wave gather staging, 32 j-rows x 32 cols, block-XOR by j>>3 (8KB).
    __shared__ __align__(16) _Float16 s_T[RPB * 512];
    __shared__ __align__(16) _Float16 s_G[4 * NK * 32];

    const int tid  = threadIdx.x;
    const int wv   = tid >> 6;
    const int ln   = tid & 63;
    const int quad = ln >> 4;
    const int c16  = ln & 15;
    const int row0 = blockIdx.x * RPB;

    _Float16* __restrict__ gbuf = &s_G[wv * (NK * 32)];
    const float4v zf = {0.f, 0.f, 0.f, 0.f};

    // ---- edge B-fragments (persistent across chunks) ----
    half8 fe[8];
    #pragma unroll
    for (int r = 0; r < 8; ++r) {
        int rg = row0 + wv * 8 + r; if (rg > N - 1) rg = N - 1;
        const float* ep = edges + (size_t)rg * (NK * NE) + quad * (8 * NE) + c16;
        #pragma unroll
        for (int jj = 0; jj < 8; ++jj) fe[r][jj] = (_Float16)ep[jj * NE];
    }

    // ---- neighbor row byte-offsets: lane stages rows j=jlane and jlane+16 ----
    const int jlane = ln >> 2;       // 0..15
    const int sub   = ln & 3;        // which 16B piece of the 64B chunk-row
    int nb0[8], nb1[8];
    #pragma unroll
    for (int r = 0; r < 8; ++r) {
        int rg = row0 + wv * 8 + r; if (rg > N - 1) rg = N - 1;
        nb0[r] = nlist[rg * NK + jlane]      << 8;   // *256 bytes per fp16 node row
        nb1[r] = nlist[rg * NK + 16 + jlane] << 8;
    }
    // staging write blocks, XOR by (j>>3)&3 (matches read side where j>>3 == quad)
    const int wblk0 = (sub ^ ((jlane >> 3) & 3)) << 3;
    const int wblk1 = (sub ^ (((jlane + 16) >> 3) & 3)) << 3;

    float4v a00 = zf, a01 = zf, a10 = zf, a11 = zf;
    const char* nbase = (const char*)nodes_h;

    for (int ch = 0; ch < 4; ++ch) {
        const char* cbase = nbase + ch * 64 + sub * 16;
        // ---- depth-4 rolling prefetch: 8 gathers in flight before consuming ----
        half8 ga[4], gb[4];
        #pragma unroll
        for (int p = 0; p < 4; ++p) {
            ga[p] = *(const half8*)(cbase + nb0[p]);
            gb[p] = *(const half8*)(cbase + nb1[p]);
        }
        // ================= phase 1 =================
        #pragma unroll
        for (int r = 0; r < 8; ++r) {
            const int il = wv * 8 + r;
            *(half8*)&gbuf[jlane * 32 + wblk0]        = ga[r & 3];
            *(half8*)&gbuf[(jlane + 16) * 32 + wblk1] = gb[r & 3];
            if (r < 4) {   // refill the slot just consumed (loads for r+4)
                ga[r & 3] = *(const half8*)(cbase + nb0[r + 4]);
                gb[r & 3] = *(const half8*)(cbase + nb1[r + 4]);
            }
            // per-wave buffer: DS ops from one wave complete in order; no barrier
            #pragma unroll
            for (int lt = 0; lt < 2; ++lt) {
                const int col   = lt * 16 + c16;
                const int rbase = quad * (8 * 32) + (col ^ (quad << 3));
                uint t0 = *(const unsigned short*)&gbuf[rbase + 0 * 32];
                uint t1 = *(const unsigned short*)&gbuf[rbase + 1 * 32];
                uint t2 = *(const unsigned short*)&gbuf[rbase + 2 * 32];
                uint t3 = *(const unsigned short*)&gbuf[rbase + 3 * 32];
                uint t4 = *(const unsigned short*)&gbuf[rbase + 4 * 32];
                uint t5 = *(const unsigned short*)&gbuf[rbase + 5 * 32];
                uint t6 = *(const unsigned short*)&gbuf[rbase + 6 * 32];
                uint t7 = *(const unsigned short*)&gbuf[rbase + 7 * 32];
                int4v pv;
                pv[0] = (int)(t0 | (t1 << 16));
                pv[1] = (int)(t2 | (t3 << 16));
                pv[2] = (int)(t4 | (t5 << 16));
                pv[3] = (int)(t6 | (t7 << 16));
                half8 av = __builtin_bit_cast(half8, pv);
                float4v d = __builtin_amdgcn_mfma_f32_16x16x32_f16(av, fe[r], zf, 0, 0, 0);
                // T store, permuted: c' = ltq*64 + c16*4 + g  (g contiguous -> b64)
                const int ltq  = lt * 4 + quad;
                const int cb   = ltq * 64 + c16 * 4;
                const int phys = cb ^ ((((ltq ^ il) & 7)) << 3);
                half4v hv;
                hv[0] = (_Float16)d[0]; hv[1] = (_Float16)d[1];
                hv[2] = (_Float16)d[2]; hv[3] = (_Float16)d[3];
                *(half4v*)&s_T[il * 512 + phys] = hv;
            }
        }
        __syncthreads();

        // ================= phase 2 =================
        const _Float16* wr0 = w2t + ((size_t)(wv * 2 + 0) * 16 + c16) * 2048 + ch * 512;
        const _Float16* wr1 = w2t + ((size_t)(wv * 2 + 1) * 16 + c16) * 2048 + ch * 512;
        #pragma unroll 4
        for (int kt = 0; kt < 16; ++kt) {
            const int cb2  = kt * 32 + quad * 8;
            const int mask = (((cb2 >> 6) ^ c16) & 7) << 3;
            half8 t0 = *(const half8*)&s_T[c16 * 512        + (cb2 ^ mask)];
            half8 t1 = *(const half8*)&s_T[(16 + c16) * 512 + (cb2 ^ mask)];
            half8 b0 = *(const half8*)(wr0 + cb2);
            half8 b1 = *(const half8*)(wr1 + cb2);
            a00 = __builtin_amdgcn_mfma_f32_16x16x32_f16(t0, b0, a00, 0, 0, 0);
            a10 = __builtin_amdgcn_mfma_f32_16x16x32_f16(t1, b0, a10, 0, 0, 0);
            a01 = __builtin_amdgcn_mfma_f32_16x16x32_f16(t0, b1, a01, 0, 0, 0);
            a11 = __builtin_amdgcn_mfma_f32_16x16x32_f16(t1, b1, a11, 0, 0, 0);
        }
        __syncthreads();   // before next chunk's phase 1 overwrites s_T
    }

    // ---- epilogue ----
    const float sc = 1.0f / (float)NK;
    const int mb = (wv << 5) + c16;
    #pragma unroll
    for (int g = 0; g < 4; ++g) {
        int i0 = row0 + quad * 4 + g;
        int i1 = i0 + 16;
        if (i0 < N) {
            out[(size_t)i0 * NF + mb]      = a00[g] * sc;
            out[(size_t)i0 * NF + mb + 16] = a01[g] * sc;
        }
        if (i1 < N) {
            out[(size_t)i1 * NF + mb]      = a10[g] * sc;
            out[(size_t)i1 * NF + mb + 16] = a11[g] * sc;
        }
    }
}

extern "C" void kernel_launch(void* const* d_in, const int* in_sizes, int n_in,
                              void* d_out, int out_size, void* d_ws, size_t ws_size,
                              hipStream_t stream) {
    const float* nodes = (const float*)d_in[0];
    const int*   nlist = (const int*)d_in[1];
    const float* edges = (const float*)d_in[2];
    const float* w     = (const float*)d_in[3];
    float* out = (float*)d_out;

    const int N = in_sizes[0] / NF;   // 50000

    _Float16* w2t     = (_Float16*)d_ws;                       // 512KB
    _Float16* nodes_h = (_Float16*)((char*)d_ws + 524288);     // 12.8MB

    const int n4 = (N * NF) / 4;
    k_prep_nodes<<<(n4 + 255) / 256, 256, 0, stream>>>(nodes, nodes_h, n4);
    k_prep_w<<<(NF * NF * NE) / 256, 256, 0, stream>>>(w, w2t);

    const int blocks = (N + RPB - 1) / RPB;                    // 1563
    k_mp<<<blocks, 256, 0, stream>>>(nodes_h, nlist, edges, w2t, out, N);
}